// Round 9
// baseline (4009.784 us; speedup 1.0000x reference)
//
#include <hip/hip_runtime.h>
#include <stdint.h>

typedef short short8 __attribute__((ext_vector_type(8)));
typedef short short4v __attribute__((ext_vector_type(4)));
typedef float floatx4 __attribute__((ext_vector_type(4)));

#define LOG2E 1.44269504088896340736f

__device__ __forceinline__ float bf2f(unsigned short u) {
  unsigned v = ((unsigned)u) << 16;
  return __builtin_bit_cast(float, v);
}
__device__ __forceinline__ unsigned short f2bf(float f) {
  unsigned v = __builtin_bit_cast(unsigned, f);
  v += 0x7FFFu + ((v >> 16) & 1u);   // RNE
  return (unsigned short)(v >> 16);
}
__device__ __forceinline__ float fast_exp2(float x) {
#if __has_builtin(__builtin_amdgcn_exp2f)
  return __builtin_amdgcn_exp2f(x);
#else
  return exp2f(x);
#endif
}
__device__ __forceinline__ float fast_rcp(float x) {
#if __has_builtin(__builtin_amdgcn_rcpf)
  return __builtin_amdgcn_rcpf(x);
#else
  return 1.0f / x;
#endif
}
__device__ __forceinline__ float fsig(float x) {
  return fast_rcp(1.0f + fast_exp2(-LOG2E * x));
}
__device__ __forceinline__ floatx4 mfma16(short8 a, short8 b, floatx4 c) {
  return __builtin_amdgcn_mfma_f32_16x16x32_bf16(a, b, c, 0, 0, 0);
}

// ---------------------------------------------------------------------------
// Dtype detection: f32 buffers show even-u16 "exponent" >= 0xF0 often; bf16
// 0.05-scaled weights never do. flag: 1 = f32, 0 = bf16.
// ---------------------------------------------------------------------------
__global__ __launch_bounds__(256) void detect_kernel(
    const unsigned short* __restrict__ w, int n_u16, int* __restrict__ flag)
{
  __shared__ int cnt;
  if (threadIdx.x == 0) cnt = 0;
  __syncthreads();
  int local = 0;
  for (int i = threadIdx.x * 2; i < n_u16; i += 512) {
    unsigned e = (w[i] >> 7) & 0xFF;
    if (e >= 0xF0) local++;
  }
  atomicAdd(&cnt, local);
  __syncthreads();
  if (threadIdx.x == 0) *flag = (cnt > 64) ? 1 : 0;
}

// ---------------------------------------------------------------------------
// One merged kernel canonicalizing all 14 weight tensors to bf16 in ws.
// Gate-block pre-scaling: i/f/o rows (and biases) scaled by log2(e), g rows
// by 2*log2(e) -> recurrence needs only bare exp2; cell state carried in the
// 2*log2(e)*c domain. fc weights (12,13) stay unscaled.
// ---------------------------------------------------------------------------
__global__ __launch_bounds__(256) void convertw_kernel(
    const void* s0, const void* s1, const void* s2, const void* s3,
    const void* s4, const void* s5, const void* s6, const void* s7,
    const void* s8, const void* s9, const void* s10, const void* s11,
    const void* s12, const void* s13,
    unsigned short* __restrict__ wbuf, const int* __restrict__ flag)
{
  const void* srcs[14] = {s0, s1, s2, s3, s4, s5, s6, s7, s8, s9, s10, s11, s12, s13};
  const int woff[14] = {0,      49152,  114688, 115200, 164352, 229888,
                        230400, 361472, 427008, 427520, 558592, 624128,
                        624640, 624896};
  const int wlen[14] = {49152, 65536, 512, 49152, 65536, 512,
                        131072, 65536, 512, 131072, 65536, 512, 256, 1};
  const int glen[14] = {96 * 128, 128 * 128, 128, 96 * 128, 128 * 128, 128,
                        256 * 128, 128 * 128, 128, 256 * 128, 128 * 128, 128,
                        0, 0};
  int sb = 0, i = 0;
  for (i = 0; i < 14; ++i) {
    int nb = (wlen[i] + 1023) >> 10;
    if ((int)blockIdx.x < sb + nb) break;
    sb += nb;
  }
  const int base = ((int)blockIdx.x - sb) * 1024 + (int)threadIdx.x * 4;
  unsigned short* dst = wbuf + woff[i];
  const int f32 = *flag;
  const int gl = glen[i];
#pragma unroll
  for (int j = 0; j < 4; ++j) {
    const int idx = base + j;
    if (idx >= wlen[i]) break;
    float v = f32 ? ((const float*)srcs[i])[idx]
                  : bf2f(((const unsigned short*)srcs[i])[idx]);
    if (gl) {
      const int gate = (int)((unsigned)idx / (unsigned)gl);  // row >> 7
      v *= (gate == 2) ? (2.0f * LOG2E) : LOG2E;
    }
    dst[idx] = f2bf(v);
  }
}

// ---------------------------------------------------------------------------
// GEMM body for 512-thread blocks: all 8 waves stage A into LDS, then all 8
// compute 512 cols (8 waves x 64). Z output bf16, per-(t,dir,bg) slab of
// 8192 shorts laid out [bh(4)][unit(128)][q(4)][gate(4)]:
//   offset = bh*2048 + u*16 + q*4 + g
// so each rec thread reads ONE contiguous 8B quad (4 gates x 1 row), a wave
// covers a contiguous 512B, and the four bh sibling blocks touch disjoint
// 4KB sub-slabs (round-6 lesson: sharing cache lines across sibling CUs
// doubles HBM fetch).
// ---------------------------------------------------------------------------
template <int K>
__device__ __forceinline__ void gemm512_body(
    unsigned short* As, int t, int slice,
    const void* __restrict__ A, size_t a_off, int dyn,
    const int* __restrict__ flag,
    const unsigned short* __restrict__ Bf, const unsigned short* __restrict__ Bb,
    const unsigned short* __restrict__ biasf, const unsigned short* __restrict__ biasb,
    unsigned short* __restrict__ Z)
{
  constexpr int RS = K + 8;
  const int tid = threadIdx.x, lane = tid & 63;
  const int q = lane >> 4, cc = lane & 15;
  constexpr int K8 = K / 8;
  const int use32 = dyn ? *flag : 0;   // wave-uniform
  if (use32) {
    const float* Arow = (const float*)A + a_off + (size_t)t * 64 * K;
    for (int ci = tid; ci < 64 * K8; ci += 512) {
      int r_ = ci / K8, c8 = ci % K8;
      const float* p = Arow + r_ * K + c8 * 8;
      floatx4 x0 = *(const floatx4*)p;
      floatx4 x1 = *(const floatx4*)(p + 4);
      short8 s;
#pragma unroll
      for (int j = 0; j < 4; ++j) {
        s[j] = (short)f2bf(x0[j]);
        s[4 + j] = (short)f2bf(x1[j]);
      }
      *(short8*)&As[r_ * RS + c8 * 8] = s;
    }
  } else {
    const unsigned short* Arow = (const unsigned short*)A + a_off + (size_t)t * 64 * K;
    for (int ci = tid; ci < 64 * K8; ci += 512) {
      int r_ = ci / K8, c8 = ci % K8;
      *(short8*)&As[r_ * RS + c8 * 8] = *(const short8*)&Arow[r_ * K + c8 * 8];
    }
  }
  __syncthreads();
  const int w = tid >> 6;
  const unsigned short* Bp    = slice ? Bb : Bf;
  const unsigned short* biasp = slice ? biasb : biasf;
  const int cb = w * 64;
  const int dslab = slice * 4;
  floatx4 acc[4][4];
#pragma unroll
  for (int m = 0; m < 4; ++m)
#pragma unroll
    for (int n = 0; n < 4; ++n)
#pragma unroll
      for (int r = 0; r < 4; ++r) acc[m][n][r] = 0.f;
#pragma unroll
  for (int ks = 0; ks < K / 32; ++ks) {
    short8 af[4], bfr[4];
#pragma unroll
    for (int m = 0; m < 4; ++m)
      af[m] = *(const short8*)&As[(m * 16 + cc) * RS + ks * 32 + q * 8];
#pragma unroll
    for (int n = 0; n < 4; ++n)
      bfr[n] = *(const short8*)&Bp[(size_t)(cb + n * 16 + cc) * K + ks * 32 + q * 8];
#pragma unroll
    for (int m = 0; m < 4; ++m)
#pragma unroll
      for (int n = 0; n < 4; ++n)
        acc[m][n] = mfma16(af[m], bfr[n], acc[m][n]);
  }
#pragma unroll
  for (int n = 0; n < 4; ++n) {
    const int col = cb + n * 16 + cc;
    const float bv = bf2f(biasp[col]);
    const int g = col >> 7, uu = col & 127;
#pragma unroll
    for (int m = 0; m < 4; ++m) {
      unsigned short* zb =
          Z + ((size_t)t * 8 + dslab + m) * 8192 + uu * 16 + q * 4 + g;
#pragma unroll
      for (int r = 0; r < 4; ++r)
        zb[r * 2048] = f2bf(acc[m][n][r] + bv);   // bh=r sub-slab
    }
  }
}

// ---------------------------------------------------------------------------
// FC body (512 threads): block idx covers timesteps idx*2 and idx*2+1.
// ---------------------------------------------------------------------------
__device__ __forceinline__ void fc512_body(
    int idx, int steps, const unsigned short* __restrict__ ys1,
    const unsigned short* __restrict__ fcw, const unsigned short* __restrict__ fcb,
    void* __restrict__ out, size_t out_off, const int* __restrict__ flag)
{
  const int tid = threadIdx.x;
  const int w = tid >> 6, lane = tid & 63;
  const int t = idx * 2 + (w >> 2);
  if (t >= steps) return;
  const int w4 = w & 3;
  const int o = lane & 15, q = lane >> 4;
  const int b = w4 * 16 + o;
  const unsigned short* rp = ys1 + ((size_t)t * 64 + b) * 256 + q * 64;
  float s = 0.f;
#pragma unroll
  for (int j = 0; j < 16; ++j) {
    short4v v = *(const short4v*)(rp + j * 4);
    const unsigned short* wp = fcw + q * 64 + j * 4;
#pragma unroll
    for (int k = 0; k < 4; ++k) s += bf2f((unsigned short)v[k]) * bf2f(wp[k]);
  }
  s += __shfl_xor(s, 16, 64);
  s += __shfl_xor(s, 32, 64);
  if (q == 0) {
    const float v = fsig(s + bf2f(fcb[0]));
    const size_t oidx = out_off + (size_t)t * 64 + b;
    if (*flag) ((float*)out)[oidx] = v;
    else       ((unsigned short*)out)[oidx] = f2bf(v);
  }
}

// ---------------------------------------------------------------------------
// Fused pipeline kernel, 512-thread blocks (8 waves, 2 waves/SIMD).
// Blocks 0..31: MERGED recurrence: block = (d, bg, bh) runs BOTH the L0
// (ctx a) and L1 (ctx b) chains at the round-8 4x-batch-split footprint
// (1 row/thread). Round 8 showed the period is ~1000 cyc exposed latency +
// ~370 cyc issue; the two chains are independent, so interleaving them in
// ONE basic block lets a's trans-latency hide under b's MFMA/DS and vice
// versa. Round-3's failure causes removed: (a) registers - at 1 row/thread
// the merged set is ~224 <= 256 budget (waves_per_eu(2,4); 2x bfrag ->
// AGPR); (b) basic-block fragmentation - the loop body is BRANCHLESS
// (inactive ctx computes garbage into always-mapped buffers; every such
// write target is dead or rewritten before any consumer; persistent
// c/h stores gated outside the loop).
// Tile-row remap: each block's 4 batch rows (q*4+bh) are stored at MFMA
// tile rows q*4 (A-row permutation => same D-row permutation), so the owned
// output is always register 0 - no runtime-indexed registers, no switch.
// Z slab [bh(4)][u][q][g] as round 8; prefetch 2 named sets/ctx.
// Blocks 32+: g96(c+1), g256(c-1), fc(c-3) workers (parity-disjoint buffers).
// ---------------------------------------------------------------------------
__global__ __attribute__((amdgpu_waves_per_eu(2, 4))) __launch_bounds__(512)
void rec_kernel(
    const unsigned short* __restrict__ Za, const unsigned short* __restrict__ whhfa,
    const unsigned short* __restrict__ whhba,
    unsigned short* __restrict__ ysa, float* __restrict__ ca,
    unsigned short* __restrict__ ha, int inita, int acta,
    const unsigned short* __restrict__ Zb, const unsigned short* __restrict__ whhfb,
    const unsigned short* __restrict__ whhbb,
    unsigned short* __restrict__ ysb, float* __restrict__ cb_,
    unsigned short* __restrict__ hb, int initb, int actb,
    int steps,
    const void* __restrict__ x, size_t x_off, int do96, const int* __restrict__ flag,
    const unsigned short* __restrict__ wih0f, const unsigned short* __restrict__ wih0b,
    const unsigned short* __restrict__ b0f, const unsigned short* __restrict__ b0b,
    unsigned short* __restrict__ Z0n,
    const unsigned short* __restrict__ ys0g, int do256,
    const unsigned short* __restrict__ wih1f, const unsigned short* __restrict__ wih1b,
    const unsigned short* __restrict__ b1f, const unsigned short* __restrict__ b1b,
    unsigned short* __restrict__ Z1n,
    const unsigned short* __restrict__ fcsrc,
    const unsigned short* __restrict__ fcw, const unsigned short* __restrict__ fcb,
    void* __restrict__ out, size_t fc_off, int fcn)
{
  __shared__ __align__(16) unsigned char smem[34816];
  const int bx = blockIdx.x;
  const int g96n = steps * 2;

  if (bx >= 32) {
    const int wi = bx - 32;
    if (wi < g96n) {                       // g96 (next chunk L0)
      if (!do96) return;
      gemm512_body<96>((unsigned short*)smem, wi >> 1, wi & 1, x, x_off, 1,
                       flag, wih0f, wih0b, b0f, b0b, Z0n);
    } else if (wi < 2 * g96n) {            // g256 (L1 chunk c-1)
      if (!do256) return;
      const int idx = wi - g96n;
      gemm512_body<256>((unsigned short*)smem, idx >> 1, idx & 1, ys0g, 0, 0,
                        flag, wih1f, wih1b, b1f, b1b, Z1n);
    } else {                               // fc (chunk c-3)
      if (fcn <= 0) return;
      fc512_body(wi - 2 * g96n, steps, fcsrc, fcw, fcb, out, fc_off, flag);
    }
    return;
  }

  // ---- merged recurrence path: block = (d, bg, bh), both ctx ----
  if (!acta && !actb) return;
  const int tid = threadIdx.x;
  const int d = bx >> 4, bg = (bx >> 2) & 3, bh = bx & 3;

  unsigned short (*hbA)[16][136] = (unsigned short(*)[16][136])smem;
  unsigned short (*hbB)[16][136] = (unsigned short(*)[16][136])(smem + 8704);

  const int w = tid >> 6, lane = tid & 63, q = lane >> 4, cc = lane & 15;
  const int u = w * 16 + cc;
  const int trow = (tid >> 7) * 4;          // tile row (0,4,8,12)
  const int prow = trow + bh;               // physical batch row
  const int pcol = tid & 127;

  // Whh as MFMA B-fragments for BOTH ctx (128 regs -> AGPR file).
  const unsigned short* whA = d ? whhba : whhfa;
  const unsigned short* whB = d ? whhbb : whhfb;
  short8 bfA[4][4], bfB[4][4];
#pragma unroll
  for (int g = 0; g < 4; ++g)
#pragma unroll
    for (int k = 0; k < 4; ++k) {
      bfA[g][k] = *(const short8*)(whA + (size_t)(g * 128 + u) * 128 + k * 32 + q * 8);
      bfB[g][k] = *(const short8*)(whB + (size_t)(g * 128 + u) * 128 + k * 32 + q * 8);
    }

  // zero BOTH ctx's hbuf double-buffers (unused tile rows must stay 0)
  {
    unsigned* hz = (unsigned*)smem;
    for (int i = tid; i < 4352; i += 512) hz[i] = 0u;
  }
  __syncthreads();

  float cregA, cregB;                // cell state, 2*log2(e)*c domain
  if (inita) {
    cregA = 0.f;
  } else {
    cregA = ca[(size_t)(d * 64 + bg * 16 + q * 4 + bh) * 128 + u];
    hbA[0][trow][pcol] = ha[(size_t)(d * 64 + bg * 16 + prow) * 128 + pcol];
  }
  if (initb) {
    cregB = 0.f;
  } else {
    cregB = cb_[(size_t)(d * 64 + bg * 16 + q * 4 + bh) * 128 + u];
    hbB[0][trow][pcol] = hb[(size_t)(d * 64 + bg * 16 + prow) * 128 + pcol];
  }
  __syncthreads();

  // per-thread z: ONE contiguous 8B quad per ctx
  const size_t zoff =
      (size_t)(d * 4 + bg) * 8192 + (size_t)bh * 2048 + u * 16 + q * 4;
  const unsigned short* zpAa = Za + zoff;           // ctx a, even steps
  const unsigned short* zpBa = Za + zoff + 65536;   // ctx a, odd steps
  const unsigned short* zpAb = Zb + zoff;
  const unsigned short* zpBb = Zb + zoff + 65536;
  short4v zAa = *(const short4v*)zpAa;
  short4v zBa = *(const short4v*)zpBa;
  short4v zAb = *(const short4v*)zpAb;
  short4v zBb = *(const short4v*)zpBb;
  zpAa += 131072; zpBa += 131072; zpAb += 131072; zpBb += 131072;

  unsigned short* ysA_ = ysa + (size_t)(bg * 16 + prow) * 256 + d * 128 + pcol;
  unsigned short* ysB_ = ysb + (size_t)(bg * 16 + prow) * 256 + d * 128 + pcol;

  // one merged timestep (both ctx); cur/nxt compile-time at call sites.
  auto half_step = [&](short4v& za_, const unsigned short*& zpa_,
                       short4v& zb_, const unsigned short*& zpb_,
                       int t, int cur, int nxt) __attribute__((always_inline)) {
    floatx4 accA[4], accB[4];
#pragma unroll
    for (int g = 0; g < 4; ++g) {
      accA[g][0] = bf2f((unsigned short)za_[g]);
      accA[g][1] = 0.f; accA[g][2] = 0.f; accA[g][3] = 0.f;
      accB[g][0] = bf2f((unsigned short)zb_[g]);
      accB[g][1] = 0.f; accB[g][2] = 0.f; accB[g][3] = 0.f;
    }
    // prefetch both sets' t+2 data; vmcnt waits land two periods away
    za_ = *(const short4v*)zpa_; zpa_ += 131072;
    zb_ = *(const short4v*)zpb_; zpb_ += 131072;

#pragma unroll
    for (int k = 0; k < 4; ++k) {
      short8 afA = *(const short8*)&hbA[cur][cc][k * 32 + q * 8];
#pragma unroll
      for (int g = 0; g < 4; ++g) accA[g] = mfma16(afA, bfA[g][k], accA[g]);
    }
#pragma unroll
    for (int k = 0; k < 4; ++k) {
      short8 afB = *(const short8*)&hbB[cur][cc][k * 32 + q * 8];
#pragma unroll
      for (int g = 0; g < 4; ++g) accB[g] = mfma16(afB, bfB[g][k], accB[g]);
    }

    // fused pointwise, ctx a (owned output = register 0 via tile-row remap)
    {
      const float ei = fast_exp2(accA[0][0]);
      const float ef = fast_exp2(accA[1][0]);
      const float eg = fast_exp2(accA[2][0]);
      const float a1 = 1.0f + ei, a2 = 1.0f + eg, a3 = 1.0f + ef;
      const float p12 = a1 * a2;
      const float rD = fast_rcp(p12 * a3);
      const float t2 = __builtin_fmaf(eg, 2.0f * LOG2E, -2.0f * LOG2E);
      const float it2 = ei * t2 * (a3 * rD);
      const float sf = ef * (p12 * rD);
      const float cs = __builtin_fmaf(sf, cregA, it2);
      cregA = cs;
      const float eo = fast_exp2(accA[3][0]);
      const float ec = fast_exp2(fminf(cs, 88.0f));
      const float h = eo * (ec - 1.0f) * fast_rcp((1.0f + eo) * (1.0f + ec));
      hbA[nxt][q * 4][u] = f2bf(h);
    }
    // fused pointwise, ctx b
    {
      const float ei = fast_exp2(accB[0][0]);
      const float ef = fast_exp2(accB[1][0]);
      const float eg = fast_exp2(accB[2][0]);
      const float a1 = 1.0f + ei, a2 = 1.0f + eg, a3 = 1.0f + ef;
      const float p12 = a1 * a2;
      const float rD = fast_rcp(p12 * a3);
      const float t2 = __builtin_fmaf(eg, 2.0f * LOG2E, -2.0f * LOG2E);
      const float it2 = ei * t2 * (a3 * rD);
      const float sf = ef * (p12 * rD);
      const float cs = __builtin_fmaf(sf, cregB, it2);
      cregB = cs;
      const float eo = fast_exp2(accB[3][0]);
      const float ec = fast_exp2(fminf(cs, 88.0f));
      const float h = eo * (ec - 1.0f) * fast_rcp((1.0f + eo) * (1.0f + ec));
      hbB[nxt][q * 4][u] = f2bf(h);
    }
    // LDS-only barrier: drain ds ops; z prefetches (vmcnt) stay in flight
    asm volatile("s_waitcnt lgkmcnt(0)\n\ts_barrier" ::: "memory");
    // drain ys rows t for both ctx - fire-and-forget stores
    ysA_[(size_t)t * 16384] = hbA[nxt][trow][pcol];
    ysB_[(size_t)t * 16384] = hbB[nxt][trow][pcol];
  };

  int t = 0;
  for (; t + 2 <= steps; t += 2) {
    half_step(zAa, zpAa, zAb, zpAb, t, 0, 1);
    half_step(zBa, zpBa, zBb, zpBb, t + 1, 1, 0);
  }
  if (t < steps)                      // odd-step tail (C=1 fallback only)
    half_step(zAa, zpAa, zAb, zpAb, t, 0, 1);

  const int fin = steps & 1;
  if (acta) {
    ca[(size_t)(d * 64 + bg * 16 + q * 4 + bh) * 128 + u] = cregA;
    ha[(size_t)(d * 64 + bg * 16 + prow) * 128 + pcol] = hbA[fin][trow][pcol];
  }
  if (actb) {
    cb_[(size_t)(d * 64 + bg * 16 + q * 4 + bh) * 128 + u] = cregB;
    hb[(size_t)(d * 64 + bg * 16 + prow) * 128 + pcol] = hbB[fin][trow][pcol];
  }
}

// ---------------------------------------------------------------------------
// Standalone gemm96 (chunk 0 prologue). Grid 2C x 512.
// ---------------------------------------------------------------------------
__global__ __attribute__((amdgpu_waves_per_eu(2, 4))) __launch_bounds__(512)
void g96_kernel(
    const void* __restrict__ x, size_t x_off, const int* __restrict__ flag,
    const unsigned short* __restrict__ Bf, const unsigned short* __restrict__ Bb,
    const unsigned short* __restrict__ biasf, const unsigned short* __restrict__ biasb,
    unsigned short* __restrict__ Z)
{
  __shared__ __align__(16) unsigned short As[64 * 104];
  gemm512_body<96>(As, blockIdx.x >> 1, blockIdx.x & 1, x, x_off, 1, flag,
                   Bf, Bb, biasf, biasb, Z);
}

// ---------------------------------------------------------------------------
// Standalone FC (final chunk). One wave per (t,b).
// ---------------------------------------------------------------------------
__global__ __launch_bounds__(256) void fc_kernel(
    const unsigned short* __restrict__ ys,
    const unsigned short* __restrict__ fcw,
    const unsigned short* __restrict__ fcb,
    void* __restrict__ out, size_t out_off, int n,
    const int* __restrict__ flag)
{
  const int gw = (int)((blockIdx.x * 256 + threadIdx.x) >> 6);
  const int lane = threadIdx.x & 63;
  if (gw >= n) return;
  const unsigned short* rp = ys + (size_t)gw * 256 + lane * 4;
  float s = 0.f;
#pragma unroll
  for (int i = 0; i < 4; ++i) s += bf2f(rp[i]) * bf2f(fcw[lane * 4 + i]);
#pragma unroll
  for (int m = 32; m >= 1; m >>= 1) s += __shfl_xor(s, m, 64);
  if (lane == 0) {
    const float v = fsig(s + bf2f(fcb[0]));
    if (*flag) ((float*)out)[out_off + gw] = v;
    else       ((unsigned short*)out)[out_off + gw] = f2bf(v);
  }
}

extern "C" void kernel_launch(void* const* d_in, const int* in_sizes, int n_in,
                              void* d_out, int out_size, void* d_ws, size_t ws_size,
                              hipStream_t stream)
{
  (void)in_sizes; (void)n_in; (void)out_size;
  const int S = 4096;

  int* flag = (int*)d_ws;
  unsigned short* wbuf = (unsigned short*)((char*)d_ws + 256);
  static const int woff[14] = {0,      49152,  114688, 115200, 164352, 229888,
                               230400, 361472, 427008, 427520, 558592, 624128,
                               624640, 624896};
  const size_t wbuf_end = 256 + 1250304;  // bytes

  // Double buffers: Z0/Z1 2*C*131072 B each, ys0/ys1 2*C*32768 each
  // -> C*655360 B.
  int C = 1;
  for (int cand = 128; cand >= 1; cand >>= 1) {
    size_t need = (size_t)cand * 655360 + wbuf_end + 196608;
    if (need <= ws_size) { C = cand; break; }
  }
  unsigned short* base = (unsigned short*)((char*)d_ws + wbuf_end);
  unsigned short* Z0buf[2] = {base, base + (size_t)C * 65536};
  unsigned short* Z1buf[2] = {base + (size_t)2 * C * 65536, base + (size_t)3 * C * 65536};
  unsigned short* ys0buf[2] = {base + (size_t)4 * C * 65536,
                               base + (size_t)4 * C * 65536 + (size_t)C * 16384};
  unsigned short* ys1buf[2] = {base + (size_t)4 * C * 65536 + (size_t)2 * C * 16384,
                               base + (size_t)4 * C * 65536 + (size_t)3 * C * 16384};
  float* c0 = (float*)(base + (size_t)4 * C * 65536 + (size_t)4 * C * 16384);
  float* c1 = c0 + 16384;
  unsigned short* h0 = (unsigned short*)(c1 + 16384);
  unsigned short* h1 = h0 + 16384;

  const unsigned short* wih0f = wbuf + woff[0];
  const unsigned short* whh0f = wbuf + woff[1];
  const unsigned short* b0f   = wbuf + woff[2];
  const unsigned short* wih0b = wbuf + woff[3];
  const unsigned short* whh0b = wbuf + woff[4];
  const unsigned short* b0b   = wbuf + woff[5];
  const unsigned short* wih1f = wbuf + woff[6];
  const unsigned short* whh1f = wbuf + woff[7];
  const unsigned short* b1f   = wbuf + woff[8];
  const unsigned short* wih1b = wbuf + woff[9];
  const unsigned short* whh1b = wbuf + woff[10];
  const unsigned short* b1b   = wbuf + woff[11];
  const unsigned short* fcw   = wbuf + woff[12];
  const unsigned short* fcb   = wbuf + woff[13];

  detect_kernel<<<1, 256, 0, stream>>>((const unsigned short*)d_in[1], 49152, flag);
  convertw_kernel<<<614, 256, 0, stream>>>(
      d_in[1], d_in[2], d_in[3], d_in[4], d_in[5], d_in[6], d_in[7],
      d_in[8], d_in[9], d_in[10], d_in[11], d_in[12], d_in[13], d_in[14],
      wbuf, flag);

  const int nc = S / C;
  // prologue: gemm96 for chunk 0
  g96_kernel<<<C * 2, 512, 0, stream>>>(d_in[0], 0, flag,
                                        wih0f, wih0b, b0f, b0b, Z0buf[0]);

  const int GX = 32 + 4 * C + (C + 1) / 2;
  for (int c = 0; c <= nc + 1; ++c) {
    const int p = c & 1, pn = (c + 1) & 1;  // pn == (c-1)&1 == (c+1)&1
    rec_kernel<<<GX, 512, 0, stream>>>(
        // ctx a: L0 chunk c
        Z0buf[p], whh0f, whh0b, ys0buf[p], c0, h0, (c == 0) ? 1 : 0,
        (c <= nc - 1) ? 1 : 0,
        // ctx b: L1 chunk c-2
        Z1buf[p], whh1f, whh1b, ys1buf[p], c1, h1, (c == 2) ? 1 : 0,
        (c >= 2) ? 1 : 0,
        C,
        // embedded g96: chunk c+1
        d_in[0], (size_t)(c + 1) * C * 6144, (c <= nc - 2) ? 1 : 0, flag,
        wih0f, wih0b, b0f, b0b, Z0buf[pn],
        // embedded g256: chunk c-1 (ys0[(c-1)&1] -> Z1[(c-1)&1])
        ys0buf[pn], (c >= 1 && c <= nc) ? 1 : 0, wih1f, wih1b, b1f, b1b, Z1buf[pn],
        // embedded fc: chunk c-3 (reads ys1[(c-3)&1])
        ys1buf[pn], fcw, fcb, d_out,
        (c >= 3) ? (size_t)(c - 3) * C * 64 : 0, (c >= 3) ? C * 64 : 0);
  }
  // tail fc: chunk nc-1 (written during rec launch nc+1)
  fc_kernel<<<C * 16, 256, 0, stream>>>(ys1buf[(nc - 1) & 1], fcw, fcb, d_out,
                                        (size_t)(nc - 1) * C * 64, C * 64, flag);
}

// Round 10
// 2451.764 us; speedup vs baseline: 1.6355x; 1.6355x over previous
//
#include <hip/hip_runtime.h>
#include <stdint.h>

typedef short short8 __attribute__((ext_vector_type(8)));
typedef short short4v __attribute__((ext_vector_type(4)));
typedef float floatx4 __attribute__((ext_vector_type(4)));

#define LOG2E 1.44269504088896340736f

__device__ __forceinline__ float bf2f(unsigned short u) {
  unsigned v = ((unsigned)u) << 16;
  return __builtin_bit_cast(float, v);
}
__device__ __forceinline__ unsigned short f2bf(float f) {
  unsigned v = __builtin_bit_cast(unsigned, f);
  v += 0x7FFFu + ((v >> 16) & 1u);   // RNE
  return (unsigned short)(v >> 16);
}
__device__ __forceinline__ float fast_exp2(float x) {
#if __has_builtin(__builtin_amdgcn_exp2f)
  return __builtin_amdgcn_exp2f(x);
#else
  return exp2f(x);
#endif
}
__device__ __forceinline__ float fast_rcp(float x) {
#if __has_builtin(__builtin_amdgcn_rcpf)
  return __builtin_amdgcn_rcpf(x);
#else
  return 1.0f / x;
#endif
}
__device__ __forceinline__ float fsig(float x) {
  return fast_rcp(1.0f + fast_exp2(-LOG2E * x));
}
__device__ __forceinline__ floatx4 mfma16(short8 a, short8 b, floatx4 c) {
  return __builtin_amdgcn_mfma_f32_16x16x32_bf16(a, b, c, 0, 0, 0);
}

// ---------------------------------------------------------------------------
// Dtype detection: f32 buffers show even-u16 "exponent" >= 0xF0 often; bf16
// 0.05-scaled weights never do. flag: 1 = f32, 0 = bf16.
// ---------------------------------------------------------------------------
__global__ __launch_bounds__(256) void detect_kernel(
    const unsigned short* __restrict__ w, int n_u16, int* __restrict__ flag)
{
  __shared__ int cnt;
  if (threadIdx.x == 0) cnt = 0;
  __syncthreads();
  int local = 0;
  for (int i = threadIdx.x * 2; i < n_u16; i += 512) {
    unsigned e = (w[i] >> 7) & 0xFF;
    if (e >= 0xF0) local++;
  }
  atomicAdd(&cnt, local);
  __syncthreads();
  if (threadIdx.x == 0) *flag = (cnt > 64) ? 1 : 0;
}

// ---------------------------------------------------------------------------
// One merged kernel canonicalizing all 14 weight tensors to bf16 in ws.
// Gate-block pre-scaling: i/f/o rows (and biases) scaled by log2(e), g rows
// by 2*log2(e) -> recurrence needs only bare exp2; cell state carried in the
// 2*log2(e)*c domain. fc weights (12,13) stay unscaled.
// ---------------------------------------------------------------------------
__global__ __launch_bounds__(256) void convertw_kernel(
    const void* s0, const void* s1, const void* s2, const void* s3,
    const void* s4, const void* s5, const void* s6, const void* s7,
    const void* s8, const void* s9, const void* s10, const void* s11,
    const void* s12, const void* s13,
    unsigned short* __restrict__ wbuf, const int* __restrict__ flag)
{
  const void* srcs[14] = {s0, s1, s2, s3, s4, s5, s6, s7, s8, s9, s10, s11, s12, s13};
  const int woff[14] = {0,      49152,  114688, 115200, 164352, 229888,
                        230400, 361472, 427008, 427520, 558592, 624128,
                        624640, 624896};
  const int wlen[14] = {49152, 65536, 512, 49152, 65536, 512,
                        131072, 65536, 512, 131072, 65536, 512, 256, 1};
  const int glen[14] = {96 * 128, 128 * 128, 128, 96 * 128, 128 * 128, 128,
                        256 * 128, 128 * 128, 128, 256 * 128, 128 * 128, 128,
                        0, 0};
  int sb = 0, i = 0;
  for (i = 0; i < 14; ++i) {
    int nb = (wlen[i] + 1023) >> 10;
    if ((int)blockIdx.x < sb + nb) break;
    sb += nb;
  }
  const int base = ((int)blockIdx.x - sb) * 1024 + (int)threadIdx.x * 4;
  unsigned short* dst = wbuf + woff[i];
  const int f32 = *flag;
  const int gl = glen[i];
#pragma unroll
  for (int j = 0; j < 4; ++j) {
    const int idx = base + j;
    if (idx >= wlen[i]) break;
    float v = f32 ? ((const float*)srcs[i])[idx]
                  : bf2f(((const unsigned short*)srcs[i])[idx]);
    if (gl) {
      const int gate = (int)((unsigned)idx / (unsigned)gl);  // row >> 7
      v *= (gate == 2) ? (2.0f * LOG2E) : LOG2E;
    }
    dst[idx] = f2bf(v);
  }
}

// ---------------------------------------------------------------------------
// GEMM body for 512-thread blocks: all 8 waves stage A into LDS, then all 8
// compute 512 cols (8 waves x 64). Z output bf16, per-(t,dir,bg) slab of
// 8192 shorts laid out [bh(4)][unit(128)][q(4)][gate(4)]:
//   offset = bh*2048 + u*16 + q*4 + g
// so each rec thread reads ONE contiguous 8B quad (4 gates x 1 row), a wave
// covers a contiguous 512B, and the four bh sibling blocks touch disjoint
// 4KB sub-slabs (round-6 lesson: sharing cache lines across sibling CUs
// doubles HBM fetch).
// ---------------------------------------------------------------------------
template <int K>
__device__ __forceinline__ void gemm512_body(
    unsigned short* As, int t, int slice,
    const void* __restrict__ A, size_t a_off, int dyn,
    const int* __restrict__ flag,
    const unsigned short* __restrict__ Bf, const unsigned short* __restrict__ Bb,
    const unsigned short* __restrict__ biasf, const unsigned short* __restrict__ biasb,
    unsigned short* __restrict__ Z)
{
  constexpr int RS = K + 8;
  const int tid = threadIdx.x, lane = tid & 63;
  const int q = lane >> 4, cc = lane & 15;
  constexpr int K8 = K / 8;
  const int use32 = dyn ? *flag : 0;   // wave-uniform
  if (use32) {
    const float* Arow = (const float*)A + a_off + (size_t)t * 64 * K;
    for (int ci = tid; ci < 64 * K8; ci += 512) {
      int r_ = ci / K8, c8 = ci % K8;
      const float* p = Arow + r_ * K + c8 * 8;
      floatx4 x0 = *(const floatx4*)p;
      floatx4 x1 = *(const floatx4*)(p + 4);
      short8 s;
#pragma unroll
      for (int j = 0; j < 4; ++j) {
        s[j] = (short)f2bf(x0[j]);
        s[4 + j] = (short)f2bf(x1[j]);
      }
      *(short8*)&As[r_ * RS + c8 * 8] = s;
    }
  } else {
    const unsigned short* Arow = (const unsigned short*)A + a_off + (size_t)t * 64 * K;
    for (int ci = tid; ci < 64 * K8; ci += 512) {
      int r_ = ci / K8, c8 = ci % K8;
      *(short8*)&As[r_ * RS + c8 * 8] = *(const short8*)&Arow[r_ * K + c8 * 8];
    }
  }
  __syncthreads();
  const int w = tid >> 6;
  const unsigned short* Bp    = slice ? Bb : Bf;
  const unsigned short* biasp = slice ? biasb : biasf;
  const int cb = w * 64;
  const int dslab = slice * 4;
  floatx4 acc[4][4];
#pragma unroll
  for (int m = 0; m < 4; ++m)
#pragma unroll
    for (int n = 0; n < 4; ++n)
#pragma unroll
      for (int r = 0; r < 4; ++r) acc[m][n][r] = 0.f;
#pragma unroll
  for (int ks = 0; ks < K / 32; ++ks) {
    short8 af[4], bfr[4];
#pragma unroll
    for (int m = 0; m < 4; ++m)
      af[m] = *(const short8*)&As[(m * 16 + cc) * RS + ks * 32 + q * 8];
#pragma unroll
    for (int n = 0; n < 4; ++n)
      bfr[n] = *(const short8*)&Bp[(size_t)(cb + n * 16 + cc) * K + ks * 32 + q * 8];
#pragma unroll
    for (int m = 0; m < 4; ++m)
#pragma unroll
      for (int n = 0; n < 4; ++n)
        acc[m][n] = mfma16(af[m], bfr[n], acc[m][n]);
  }
#pragma unroll
  for (int n = 0; n < 4; ++n) {
    const int col = cb + n * 16 + cc;
    const float bv = bf2f(biasp[col]);
    const int g = col >> 7, uu = col & 127;
#pragma unroll
    for (int m = 0; m < 4; ++m) {
      unsigned short* zb =
          Z + ((size_t)t * 8 + dslab + m) * 8192 + uu * 16 + q * 4 + g;
#pragma unroll
      for (int r = 0; r < 4; ++r)
        zb[r * 2048] = f2bf(acc[m][n][r] + bv);   // bh=r sub-slab
    }
  }
}

// ---------------------------------------------------------------------------
// FC body (512 threads): block idx covers timesteps idx*2 and idx*2+1.
// ---------------------------------------------------------------------------
__device__ __forceinline__ void fc512_body(
    int idx, int steps, const unsigned short* __restrict__ ys1,
    const unsigned short* __restrict__ fcw, const unsigned short* __restrict__ fcb,
    void* __restrict__ out, size_t out_off, const int* __restrict__ flag)
{
  const int tid = threadIdx.x;
  const int w = tid >> 6, lane = tid & 63;
  const int t = idx * 2 + (w >> 2);
  if (t >= steps) return;
  const int w4 = w & 3;
  const int o = lane & 15, q = lane >> 4;
  const int b = w4 * 16 + o;
  const unsigned short* rp = ys1 + ((size_t)t * 64 + b) * 256 + q * 64;
  float s = 0.f;
#pragma unroll
  for (int j = 0; j < 16; ++j) {
    short4v v = *(const short4v*)(rp + j * 4);
    const unsigned short* wp = fcw + q * 64 + j * 4;
#pragma unroll
    for (int k = 0; k < 4; ++k) s += bf2f((unsigned short)v[k]) * bf2f(wp[k]);
  }
  s += __shfl_xor(s, 16, 64);
  s += __shfl_xor(s, 32, 64);
  if (q == 0) {
    const float v = fsig(s + bf2f(fcb[0]));
    const size_t oidx = out_off + (size_t)t * 64 + b;
    if (*flag) ((float*)out)[oidx] = v;
    else       ((unsigned short*)out)[oidx] = f2bf(v);
  }
}

// ---------------------------------------------------------------------------
// Fused pipeline kernel, 512-thread blocks (8 waves, 2 waves/SIMD).
// Blocks 0..63: recurrence, batch-split 4x (round-8 structure, the measured
// optimum: 73.3us/dispatch, 1374 cyc/step). Round-9 lesson folded in: waves
// issue IN-ORDER, so a second chain in the same instruction stream cannot
// hide the serial chain (only ~16% overlap at 2x work) - single-ctx blocks
// stay. Two verified micro-opts harvested from round 9:
//  (1) tile-row remap: the block's 4 physical rows {bh,4+bh,8+bh,12+bh} live
//      at tile rows {0,4,8,12}; owned MFMA output is always REGISTER 0 ->
//      no switch(bh) duplication, all indexing static.
//  (2) persistent acc rows 1-3: those D rows are fed only by all-zero A rows
//      (hbuf zero rows), so D[r]=C[r] - init once to 0, never reset: saves
//      12 v_mov per step in the critical loop.
// Z slab [bh(4)][u][q][g]: thread reads one contiguous 8B quad; wave reads
// contiguous 512B; bh siblings disjoint 4KB sub-slabs.
// Z prefetch: TWO named register sets (A/B), 2x-unrolled loop -> vmcnt wait
// lands two periods after issue.
// Blocks 64+: g96(c+1), g256(c-1), fc(c-3) workers (parity-disjoint buffers).
// ---------------------------------------------------------------------------
__global__ __attribute__((amdgpu_waves_per_eu(2, 4))) __launch_bounds__(512)
void rec_kernel(
    const unsigned short* __restrict__ Za, const unsigned short* __restrict__ whhfa,
    const unsigned short* __restrict__ whhba,
    unsigned short* __restrict__ ysa, float* __restrict__ ca,
    unsigned short* __restrict__ ha, int inita, int acta,
    const unsigned short* __restrict__ Zb, const unsigned short* __restrict__ whhfb,
    const unsigned short* __restrict__ whhbb,
    unsigned short* __restrict__ ysb, float* __restrict__ cb_,
    unsigned short* __restrict__ hb, int initb, int actb,
    int steps,
    const void* __restrict__ x, size_t x_off, int do96, const int* __restrict__ flag,
    const unsigned short* __restrict__ wih0f, const unsigned short* __restrict__ wih0b,
    const unsigned short* __restrict__ b0f, const unsigned short* __restrict__ b0b,
    unsigned short* __restrict__ Z0n,
    const unsigned short* __restrict__ ys0g, int do256,
    const unsigned short* __restrict__ wih1f, const unsigned short* __restrict__ wih1b,
    const unsigned short* __restrict__ b1f, const unsigned short* __restrict__ b1b,
    unsigned short* __restrict__ Z1n,
    const unsigned short* __restrict__ fcsrc,
    const unsigned short* __restrict__ fcw, const unsigned short* __restrict__ fcb,
    void* __restrict__ out, size_t fc_off, int fcn)
{
  __shared__ __align__(16) unsigned char smem[34816];
  const int bx = blockIdx.x;
  const int g96n = steps * 2;

  if (bx >= 64) {
    const int wi = bx - 64;
    if (wi < g96n) {                       // g96 (next chunk L0)
      if (!do96) return;
      gemm512_body<96>((unsigned short*)smem, wi >> 1, wi & 1, x, x_off, 1,
                       flag, wih0f, wih0b, b0f, b0b, Z0n);
    } else if (wi < 2 * g96n) {            // g256 (L1 chunk c-1)
      if (!do256) return;
      const int idx = wi - g96n;
      gemm512_body<256>((unsigned short*)smem, idx >> 1, idx & 1, ys0g, 0, 0,
                        flag, wih1f, wih1b, b1f, b1b, Z1n);
    } else {                               // fc (chunk c-3)
      if (fcn <= 0) return;
      fc512_body(wi - 2 * g96n, steps, fcsrc, fcw, fcb, out, fc_off, flag);
    }
    return;
  }

  // ---- recurrence path: block = (ctx, d, bg, bh) ----
  const int blk = bx;
  const int ctx = blk >> 5;
  if (ctx == 0 ? !acta : !actb) return;
  const int tid = threadIdx.x;

  const unsigned short* Z;
  const unsigned short* whhF;
  const unsigned short* whhB;
  unsigned short* ys;
  float* cst;
  unsigned short* hst;
  int init;
  if (ctx == 0) {
    Z = Za; whhF = whhfa; whhB = whhba; ys = ysa; cst = ca; hst = ha; init = inita;
  } else {
    Z = Zb; whhF = whhfb; whhB = whhbb; ys = ysb; cst = cb_; hst = hb; init = initb;
  }
  const int d = (blk >> 4) & 1, bg = (blk >> 2) & 3, bh = blk & 3;
  const unsigned short* whh = d ? whhB : whhF;

  unsigned short (*hbuf)[16][136] = (unsigned short(*)[16][136])smem;

  const int w = tid >> 6, lane = tid & 63, q = lane >> 4, cc = lane & 15;
  const int u = w * 16 + cc;

  // Whh as MFMA B-fragments, register-resident (64 regs -> AGPR file).
  short8 bfrag[4][4];
#pragma unroll
  for (int g = 0; g < 4; ++g)
#pragma unroll
    for (int k = 0; k < 4; ++k)
      bfrag[g][k] = *(const short8*)(whh + (size_t)(g * 128 + u) * 128 + k * 32 + q * 8);

  // tile-row remap: physical rows {bh,4+bh,8+bh,12+bh} at tile rows {0,4,8,12}
  const int trow = (tid >> 7) * 4;                   // tile row (0,4,8,12)
  const int prow = trow + bh;                        // physical batch row
  const int pcol = tid & 127;                        // unit column

  // zero BOTH hbuf buffers (non-{0,4,8,12} tile rows must read as 0 forever)
  {
    unsigned* hz = (unsigned*)smem;
    for (int i = tid; i < 2 * 16 * 68; i += 512) hz[i] = 0u;
  }
  __syncthreads();

  float creg;                        // 1 cell row/thread, 2*log2(e)*c domain
  if (init) {
    creg = 0.f;
  } else {
    creg = cst[(size_t)(d * 64 + bg * 16 + q * 4 + bh) * 128 + u];
    hbuf[0][trow][pcol] = hst[(size_t)(d * 64 + bg * 16 + prow) * 128 + pcol];
  }
  __syncthreads();

  // per-thread z: ONE contiguous 8B quad = 4 gates x 1 row
  const size_t zoff =
      (size_t)(d * 4 + bg) * 8192 + (size_t)bh * 2048 + u * 16 + q * 4;
  const unsigned short* zpA = Z + zoff;             // even-step addresses
  const unsigned short* zpB = Z + zoff + 65536;     // odd-step addresses
  short4v zA = *(const short4v*)zpA;
  short4v zB = *(const short4v*)zpB;
  zpA += 131072;
  zpB += 131072;

  unsigned short* ysb_ = ys + (size_t)(bg * 16 + prow) * 256 + d * 128 + pcol;

  // persistent accumulators: rows 1-3 are fed ONLY by zero A-rows -> D[r] =
  // C[r] stays 0 forever; row 0 is re-seeded with z each step.
  floatx4 acc[4];
#pragma unroll
  for (int g = 0; g < 4; ++g)
#pragma unroll
    for (int r = 0; r < 4; ++r) acc[g][r] = 0.f;

  // one timestep; cur/nxt compile-time at each call site.
  auto half_step = [&](short4v& zs, const unsigned short*& zp, int t,
                       int cur, int nxt) __attribute__((always_inline)) {
#pragma unroll
    for (int g = 0; g < 4; ++g)
      acc[g][0] = bf2f((unsigned short)zs[g]);
    // prefetch this set's t+2 data; vmcnt wait is two periods away
    zs = *(const short4v*)zp;
    zp += 131072;

    short8 af[4];
#pragma unroll
    for (int k = 0; k < 4; ++k)
      af[k] = *(const short8*)&hbuf[cur][cc][k * 32 + q * 8];
#pragma unroll
    for (int g = 0; g < 4; ++g)
#pragma unroll
      for (int k = 0; k < 4; ++k)
        acc[g] = mfma16(af[k], bfrag[g][k], acc[g]);

    // fused pointwise on the 1 owned row (register 0): 5 exp2 + 2 rcp.
    {
      const float ei = fast_exp2(acc[0][0]);
      const float ef = fast_exp2(acc[1][0]);
      const float eg = fast_exp2(acc[2][0]);
      const float a1 = 1.0f + ei, a2 = 1.0f + eg, a3 = 1.0f + ef;
      const float p12 = a1 * a2;
      const float rD = fast_rcp(p12 * a3);
      const float t2 = __builtin_fmaf(eg, 2.0f * LOG2E, -2.0f * LOG2E);
      const float it2 = ei * t2 * (a3 * rD);       // 2L * sig(i)*tanh(g)
      const float sf = ef * (p12 * rD);            // sig(f)
      const float cs = __builtin_fmaf(sf, creg, it2);
      creg = cs;
      const float eo = fast_exp2(acc[3][0]);
      const float ec = fast_exp2(fminf(cs, 88.0f));  // e^{2c}
      const float h = eo * (ec - 1.0f) * fast_rcp((1.0f + eo) * (1.0f + ec));
      hbuf[nxt][q * 4][u] = f2bf(h);               // tile row q*4 (owned)
    }
    // LDS-only barrier: drain ds ops; z prefetch (vmcnt) stays in flight
    asm volatile("s_waitcnt lgkmcnt(0)\n\ts_barrier" ::: "memory");
    // drain ys rows t (this block's 4 rows) - fire-and-forget store
    ysb_[(size_t)t * 16384] = hbuf[nxt][trow][pcol];
  };

  int t = 0;
  for (; t + 2 <= steps; t += 2) {
    half_step(zA, zpA, t, 0, 1);
    half_step(zB, zpB, t + 1, 1, 0);
  }
  if (t < steps)                      // odd-step tail (C=1 fallback only)
    half_step(zA, zpA, t, 0, 1);

  cst[(size_t)(d * 64 + bg * 16 + q * 4 + bh) * 128 + u] = creg;
  const int fin = steps & 1;
  hst[(size_t)(d * 64 + bg * 16 + prow) * 128 + pcol] = hbuf[fin][trow][pcol];
}

// ---------------------------------------------------------------------------
// Standalone gemm96 (chunk 0 prologue). Grid 2C x 512.
// ---------------------------------------------------------------------------
__global__ __attribute__((amdgpu_waves_per_eu(2, 4))) __launch_bounds__(512)
void g96_kernel(
    const void* __restrict__ x, size_t x_off, const int* __restrict__ flag,
    const unsigned short* __restrict__ Bf, const unsigned short* __restrict__ Bb,
    const unsigned short* __restrict__ biasf, const unsigned short* __restrict__ biasb,
    unsigned short* __restrict__ Z)
{
  __shared__ __align__(16) unsigned short As[64 * 104];
  gemm512_body<96>(As, blockIdx.x >> 1, blockIdx.x & 1, x, x_off, 1, flag,
                   Bf, Bb, biasf, biasb, Z);
}

// ---------------------------------------------------------------------------
// Standalone FC (final chunk). One wave per (t,b).
// ---------------------------------------------------------------------------
__global__ __launch_bounds__(256) void fc_kernel(
    const unsigned short* __restrict__ ys,
    const unsigned short* __restrict__ fcw,
    const unsigned short* __restrict__ fcb,
    void* __restrict__ out, size_t out_off, int n,
    const int* __restrict__ flag)
{
  const int gw = (int)((blockIdx.x * 256 + threadIdx.x) >> 6);
  const int lane = threadIdx.x & 63;
  if (gw >= n) return;
  const unsigned short* rp = ys + (size_t)gw * 256 + lane * 4;
  float s = 0.f;
#pragma unroll
  for (int i = 0; i < 4; ++i) s += bf2f(rp[i]) * bf2f(fcw[lane * 4 + i]);
#pragma unroll
  for (int m = 32; m >= 1; m >>= 1) s += __shfl_xor(s, m, 64);
  if (lane == 0) {
    const float v = fsig(s + bf2f(fcb[0]));
    if (*flag) ((float*)out)[out_off + gw] = v;
    else       ((unsigned short*)out)[out_off + gw] = f2bf(v);
  }
}

extern "C" void kernel_launch(void* const* d_in, const int* in_sizes, int n_in,
                              void* d_out, int out_size, void* d_ws, size_t ws_size,
                              hipStream_t stream)
{
  (void)in_sizes; (void)n_in; (void)out_size;
  const int S = 4096;

  int* flag = (int*)d_ws;
  unsigned short* wbuf = (unsigned short*)((char*)d_ws + 256);
  static const int woff[14] = {0,      49152,  114688, 115200, 164352, 229888,
                               230400, 361472, 427008, 427520, 558592, 624128,
                               624640, 624896};
  const size_t wbuf_end = 256 + 1250304;  // bytes

  // Double buffers: Z0/Z1 2*C*131072 B each, ys0/ys1 2*C*32768 each
  // -> C*655360 B.
  int C = 1;
  for (int cand = 128; cand >= 1; cand >>= 1) {
    size_t need = (size_t)cand * 655360 + wbuf_end + 196608;
    if (need <= ws_size) { C = cand; break; }
  }
  unsigned short* base = (unsigned short*)((char*)d_ws + wbuf_end);
  unsigned short* Z0buf[2] = {base, base + (size_t)C * 65536};
  unsigned short* Z1buf[2] = {base + (size_t)2 * C * 65536, base + (size_t)3 * C * 65536};
  unsigned short* ys0buf[2] = {base + (size_t)4 * C * 65536,
                               base + (size_t)4 * C * 65536 + (size_t)C * 16384};
  unsigned short* ys1buf[2] = {base + (size_t)4 * C * 65536 + (size_t)2 * C * 16384,
                               base + (size_t)4 * C * 65536 + (size_t)3 * C * 16384};
  float* c0 = (float*)(base + (size_t)4 * C * 65536 + (size_t)4 * C * 16384);
  float* c1 = c0 + 16384;
  unsigned short* h0 = (unsigned short*)(c1 + 16384);
  unsigned short* h1 = h0 + 16384;

  const unsigned short* wih0f = wbuf + woff[0];
  const unsigned short* whh0f = wbuf + woff[1];
  const unsigned short* b0f   = wbuf + woff[2];
  const unsigned short* wih0b = wbuf + woff[3];
  const unsigned short* whh0b = wbuf + woff[4];
  const unsigned short* b0b   = wbuf + woff[5];
  const unsigned short* wih1f = wbuf + woff[6];
  const unsigned short* whh1f = wbuf + woff[7];
  const unsigned short* b1f   = wbuf + woff[8];
  const unsigned short* wih1b = wbuf + woff[9];
  const unsigned short* whh1b = wbuf + woff[10];
  const unsigned short* b1b   = wbuf + woff[11];
  const unsigned short* fcw   = wbuf + woff[12];
  const unsigned short* fcb   = wbuf + woff[13];

  detect_kernel<<<1, 256, 0, stream>>>((const unsigned short*)d_in[1], 49152, flag);
  convertw_kernel<<<614, 256, 0, stream>>>(
      d_in[1], d_in[2], d_in[3], d_in[4], d_in[5], d_in[6], d_in[7],
      d_in[8], d_in[9], d_in[10], d_in[11], d_in[12], d_in[13], d_in[14],
      wbuf, flag);

  const int nc = S / C;
  // prologue: gemm96 for chunk 0
  g96_kernel<<<C * 2, 512, 0, stream>>>(d_in[0], 0, flag,
                                        wih0f, wih0b, b0f, b0b, Z0buf[0]);

  const int GX = 64 + 4 * C + (C + 1) / 2;
  for (int c = 0; c <= nc + 1; ++c) {
    const int p = c & 1, pn = (c + 1) & 1;  // pn == (c-1)&1 == (c+1)&1
    rec_kernel<<<GX, 512, 0, stream>>>(
        // ctx a: L0 chunk c
        Z0buf[p], whh0f, whh0b, ys0buf[p], c0, h0, (c == 0) ? 1 : 0,
        (c <= nc - 1) ? 1 : 0,
        // ctx b: L1 chunk c-2
        Z1buf[p], whh1f, whh1b, ys1buf[p], c1, h1, (c == 2) ? 1 : 0,
        (c >= 2) ? 1 : 0,
        C,
        // embedded g96: chunk c+1
        d_in[0], (size_t)(c + 1) * C * 6144, (c <= nc - 2) ? 1 : 0, flag,
        wih0f, wih0b, b0f, b0b, Z0buf[pn],
        // embedded g256: chunk c-1 (ys0[(c-1)&1] -> Z1[(c-1)&1])
        ys0buf[pn], (c >= 1 && c <= nc) ? 1 : 0, wih1f, wih1b, b1f, b1b, Z1buf[pn],
        // embedded fc: chunk c-3 (reads ys1[(c-3)&1])
        ys1buf[pn], fcw, fcb, d_out,
        (c >= 3) ? (size_t)(c - 3) * C * 64 : 0, (c >= 3) ? C * 64 : 0);
  }
  // tail fc: chunk nc-1 (written during rec launch nc+1)
  fc_kernel<<<C * 16, 256, 0, stream>>>(ys1buf[(nc - 1) & 1], fcw, fcb, d_out,
                                        (size_t)(nc - 1) * C * 64, C * 64, flag);
}